// Round 18
// baseline (198.598 us; speedup 1.0000x reference)
//
#include <hip/hip_runtime.h>

// ---------------------------------------------------------------------------
// GIN 3-layer forward on MI355X (gfx950).
//   - features/weights bf16 node-major (f32 accumulate). Node-major 256B rows
//     gather at ~7.2 TB/s L2-miss fabric traffic = the 8-XCD fabric ceiling
//     (R12-R16: 62us invariant across 5 structural variants; re-layout,
//     fusion, and 4-edge unroll (R17: 74us, remainder-serialization) all
//     regressed -> 2-edge loop is the tuned form).
//   - k_scatter (merged): LDS-binned edge scatter with FULL-LINE flushes
//     (sentinel-padded 64B bursts; this chip's L2 does NOT merge scattered
//     partial-line stores) + x f32->bf16 conversion + weight transpose +
//     root bitmap, all hidden under the latency-bound binning.
//   - k_build (merged): per-bucket histogram -> scan -> rp -> csr slotting,
//     flags root in-neighbors inline (af) via af_root bitmap.
//   - k_segz: max-TLP gather (2-edge unroll); tail blocks of the SAME launch
//     run the active-set compaction (saves a dispatch; R17 verified).
//   - k_mlp: MFMA 16x16x32 bf16, BM=128, 4 waves, 34.8 KB LDS; B from global
//     (L2-resident); output via LDS -> bf16x8 full-line stores.
//   - k_gmlp (layer 1, 17K rows): fused gather+MLP (imbalance tax < launch
//     + z-roundtrip saved at this size; R15/R16 measured).
//   - layer 2 only at the 1024 roots.
//   NOTE: edge packing assumes N <= 2^17; bins assume N <= 100352.
// ---------------------------------------------------------------------------

typedef __bf16  bf16x8 __attribute__((ext_vector_type(8)));
typedef float   f32x4  __attribute__((ext_vector_type(4)));

#define NBINS 784     // >= (N+127)/128
#define BCAP  38      // words per LDS bin (per-bin lambda ~8)
#define CAP   8192    // words per global bucket cell (real ~2048 + pads)
#define LDR   136     // LDS row stride in shorts (+8 pad)

// ---------------- merged scatter + conversions + root flag ----------------
__global__ __launch_bounds__(1024) void k_scatter(const int* __restrict__ src,
                                                  const int* __restrict__ dst,
                                                  int* __restrict__ gcnt,     // NB*16 padded
                                                  int* __restrict__ realcnt,  // NB
                                                  unsigned* __restrict__ ebuf,
                                                  int e, int nb,
                                                  const float4* __restrict__ xf,
                                                  unsigned short* __restrict__ xb,
                                                  long n8,
                                                  const float* __restrict__ w0a,
                                                  const float* __restrict__ w0b,
                                                  const float* __restrict__ w1a,
                                                  const float* __restrict__ w1b,
                                                  unsigned short* __restrict__ wT,
                                                  const int* __restrict__ roots,
                                                  int nr,
                                                  int* __restrict__ af_root) {
    __shared__ unsigned lbuf[NBINS * BCAP];   // 119.2 KB
    __shared__ int lcnt[NBINS];
    __shared__ int sbase[NBINS];
    const int t = threadIdx.x;
    for (int b = t; b < nb; b += 1024) lcnt[b] = 0;

    {
        int gi = blockIdx.x * 1024 + t;
        if (gi < nr) af_root[roots[gi]] = 1;
    }
    {
        int gi = blockIdx.x * 1024 + t;
        if (gi < 65536) {
            int m = gi >> 14, j = gi & 16383;
            const float* w = (m == 0) ? w0a : (m == 1) ? w0b : (m == 2) ? w1a : w1b;
            int k = j >> 7, n = j & 127;
            *(__bf16*)&wT[m * 16384 + n * 128 + k] = (__bf16)w[j];
        }
    }
    for (long i = (long)blockIdx.x * 1024 + t; i < n8; i += 262144) {
        float4 a = xf[2 * i], b = xf[2 * i + 1];
        bf16x8 v;
        v[0] = (__bf16)a.x; v[1] = (__bf16)a.y; v[2] = (__bf16)a.z; v[3] = (__bf16)a.w;
        v[4] = (__bf16)b.x; v[5] = (__bf16)b.y; v[6] = (__bf16)b.z; v[7] = (__bf16)b.w;
        *(bf16x8*)&xb[i * 8] = v;
    }
    __syncthreads();

    const int per = (((e + 255) / 256) + 7) & ~7;   // 8-aligned slice, 256 blocks
    const int beg = blockIdx.x * per;
    const int end = (beg + per < e) ? beg + per : e;

    for (int base = beg; base < end; base += 8192) {
        int i0 = base + t * 8;
        if (i0 >= end) continue;
        if (i0 + 8 <= end) {
            int4 s0 = *(const int4*)&src[i0];
            int4 s1 = *(const int4*)&src[i0 + 4];
            int4 d0 = *(const int4*)&dst[i0];
            int4 d1 = *(const int4*)&dst[i0 + 4];
            int ss[8] = {s0.x, s0.y, s0.z, s0.w, s1.x, s1.y, s1.z, s1.w};
            int dd[8] = {d0.x, d0.y, d0.z, d0.w, d1.x, d1.y, d1.z, d1.w};
#pragma unroll
            for (int q = 0; q < 8; ++q) {
                int b = dd[q] >> 7;
                int p = atomicAdd(&lcnt[b], 1);
                if (p < BCAP)
                    lbuf[b * BCAP + p] =
                        (unsigned)ss[q] | ((unsigned)(dd[q] & 127) << 17);
            }
        } else {
            int lim = (i0 + 8 < end) ? i0 + 8 : end;
            for (int i = i0; i < lim; ++i) {
                int d = dst[i];
                int b = d >> 7;
                int p = atomicAdd(&lcnt[b], 1);
                if (p < BCAP)
                    lbuf[b * BCAP + p] =
                        (unsigned)src[i] | ((unsigned)(d & 127) << 17);
            }
        }
    }
    __syncthreads();

    for (int b = t; b < nb; b += 1024) {
        int r = lcnt[b]; if (r > BCAP) r = BCAP;
        int bb = 0;
        if (r > 0) {
            int nf = (r + 15) & ~15;
            bb = atomicAdd(&gcnt[b * 16], nf);
            atomicAdd(&realcnt[b], r);
        }
        sbase[b] = bb;
    }
    __syncthreads();

    const int wave = t >> 6, lane = t & 63;
    const int gidx = wave * 4 + (lane >> 4), sub = lane & 15;
    for (int b = gidx; b < nb; b += 64) {
        int r = lcnt[b]; if (r > BCAP) r = BCAP;
        if (r == 0) continue;
        int nf = (r + 15) & ~15;
        int base2 = sbase[b];
        unsigned* cell = ebuf + (size_t)b * CAP;
        for (int j = sub; j < nf; j += 16) {
            unsigned v = (j < r) ? lbuf[b * BCAP + j] : 0xFFFFFFFFu;
            if (base2 + j < CAP) cell[base2 + j] = v;
        }
    }
}

__global__ __launch_bounds__(1024) void k_bscan(const int* __restrict__ realcnt,
                                                int* __restrict__ boff,
                                                int* __restrict__ rp,
                                                int nb, int n, int e) {
    __shared__ int sh[1024];
    int t = threadIdx.x;
    sh[t] = (t < nb) ? realcnt[t] : 0;
    __syncthreads();
    for (int off = 1; off < 1024; off <<= 1) {
        int u = (t >= off) ? sh[t - off] : 0;
        __syncthreads();
        sh[t] += u;
        __syncthreads();
    }
    if (t < nb) boff[t] = (t == 0) ? 0 : sh[t - 1];
    if (t == 0) rp[n] = e;
}

__global__ __launch_bounds__(512) void k_build(const unsigned* __restrict__ ebuf,
                                               const int* __restrict__ gcnt,
                                               const int* __restrict__ boff,
                                               int* __restrict__ rp,
                                               int* __restrict__ csr,
                                               const int* __restrict__ af_root,
                                               int* __restrict__ af, int n) {
    __shared__ int bins[128];
    __shared__ int incl[128];
    __shared__ int cur[128];
    __shared__ unsigned char isroot[128];
    int b = blockIdx.x, t = threadIdx.x;
    if (t < 128) {
        bins[t] = 0;
        int node = b * 128 + t;
        unsigned char ir = (node < n && af_root[node]) ? 1 : 0;
        isroot[t] = ir;
        if (ir) af[node] = 1;
    }
    __syncthreads();
    int c = gcnt[b * 16]; if (c > CAP) c = CAP;
    const unsigned* seg = ebuf + ((size_t)b * CAP);
    for (int j = t; j < c; j += 512) {
        unsigned w = seg[j];
        if (w != 0xFFFFFFFFu) atomicAdd(&bins[(w >> 17) & 127], 1);
    }
    __syncthreads();
    if (t < 128) incl[t] = bins[t];
    __syncthreads();
    for (int off = 1; off < 128; off <<= 1) {
        int u = (t < 128 && t >= off) ? incl[t - off] : 0;
        __syncthreads();
        if (t < 128) incl[t] += u;
        __syncthreads();
    }
    int base = boff[b];
    if (t < 128) {
        int ex = (t == 0) ? 0 : incl[t - 1];
        cur[t] = ex;
        int node = b * 128 + t;
        if (node < n) rp[node] = base + ex;
    }
    __syncthreads();
    for (int j = t; j < c; j += 512) {
        unsigned w = seg[j];
        if (w != 0xFFFFFFFFu) {
            int ldst = (w >> 17) & 127;
            int s = (int)(w & 0x1FFFF);
            int slot = atomicAdd(&cur[ldst], 1);
            csr[base + slot] = s;
            if (isroot[ldst]) af[s] = 1;
        }
    }
}

// ---------------- gather + GIN update (layer 0) + tail-block compaction ----
// Blocks [0, nsegb): z[j] = (1+eps)*x[j] + sum_{s in N(j)} x[s]; 16 lanes/row,
// 2-edge unroll (R17 lesson: 4-edge regressed via remainder serialization).
// Blocks [nsegb, ...): active-set compaction (af -> list, cnt).
__global__ __launch_bounds__(256) void k_segz(const unsigned short* __restrict__ xb,
                                              const int* __restrict__ rp,
                                              const int* __restrict__ csr,
                                              const float* __restrict__ epsp,
                                              unsigned short* __restrict__ zout,
                                              int n, int nsegb,
                                              const int* __restrict__ af,
                                              int* __restrict__ list,
                                              int* __restrict__ cnt) {
    if ((int)blockIdx.x >= nsegb) {
        int i = (blockIdx.x - nsegb) * 256 + threadIdx.x;
        if (i < n && af[i]) {
            int p = atomicAdd(cnt, 1);
            list[p] = i;
        }
        return;
    }
    int gid = blockIdx.x * 256 + threadIdx.x;
    int j = gid >> 4, lane = gid & 15;
    if (j >= n) return;
    int b = rp[j], e = rp[j + 1];
    float s0[8], s1[8];
#pragma unroll
    for (int q = 0; q < 8; ++q) { s0[q] = 0.f; s1[q] = 0.f; }
    int k = b;
    for (; k + 1 < e; k += 2) {
        bf16x8 v0 = *(const bf16x8*)&xb[(size_t)csr[k]     * 128 + lane * 8];
        bf16x8 v1 = *(const bf16x8*)&xb[(size_t)csr[k + 1] * 128 + lane * 8];
#pragma unroll
        for (int q = 0; q < 8; ++q) { s0[q] += (float)v0[q]; s1[q] += (float)v1[q]; }
    }
    if (k < e) {
        bf16x8 v0 = *(const bf16x8*)&xb[(size_t)csr[k] * 128 + lane * 8];
#pragma unroll
        for (int q = 0; q < 8; ++q) s0[q] += (float)v0[q];
    }
    const float epsv = 1.0f + epsp[0];
    bf16x8 xv = *(const bf16x8*)&xb[(size_t)j * 128 + lane * 8];
    bf16x8 o;
#pragma unroll
    for (int q = 0; q < 8; ++q)
        o[q] = (__bf16)(epsv * (float)xv[q] + s0[q] + s1[q]);
    *(bf16x8*)&zout[(size_t)j * 128 + lane * 8] = o;
}

// ---------------- MLP (layer 0): out = relu( relu(z@w1+b1) @ w2 + b2 ) ----
__global__ __launch_bounds__(256) void k_mlp(const unsigned short* __restrict__ zbuf,
                                             const unsigned short* __restrict__ w1T,
                                             const float* __restrict__ b1,
                                             const unsigned short* __restrict__ w2T,
                                             const float* __restrict__ b2,
                                             unsigned short* __restrict__ out,
                                             int nrows) {
    __shared__ unsigned short zt[128 * LDR];   // 34.8 KB
    const int t = threadIdx.x;
    const int row0 = blockIdx.x * 128;
    if (row0 >= nrows) return;

    for (int i = t; i < 2048; i += 256) {
        int r = i >> 4, c = i & 15;
        int g = row0 + r;
        bf16x8 zv;
        if (g < nrows) {
            zv = *(const bf16x8*)&zbuf[(size_t)g * 128 + c * 8];
        } else {
#pragma unroll
            for (int q = 0; q < 8; ++q) zv[q] = (__bf16)0.0f;
        }
        *(bf16x8*)&zt[r * LDR + c * 8] = zv;
    }
    __syncthreads();

    const int lane = t & 63;
    const int wm = (t >> 7) & 1, wn = (t >> 6) & 1;
    const int lr = lane & 15, lk = lane >> 4;

    f32x4 zero4 = {0.f, 0.f, 0.f, 0.f};
    f32x4 acc[4][4];
#pragma unroll
    for (int mt = 0; mt < 4; ++mt)
#pragma unroll
        for (int nt = 0; nt < 4; ++nt) acc[mt][nt] = zero4;

#pragma unroll
    for (int kb = 0; kb < 4; ++kb) {
        const int c = kb * 4 + lk;
        bf16x8 a[4];
#pragma unroll
        for (int mt = 0; mt < 4; ++mt)
            a[mt] = *(const bf16x8*)&zt[(wm * 64 + mt * 16 + lr) * LDR + c * 8];
#pragma unroll
        for (int nt = 0; nt < 4; ++nt) {
            bf16x8 b = *(const bf16x8*)&w1T[(wn * 64 + nt * 16 + lr) * 128 + c * 8];
#pragma unroll
            for (int mt = 0; mt < 4; ++mt)
                acc[mt][nt] = __builtin_amdgcn_mfma_f32_16x16x32_bf16(a[mt], b, acc[mt][nt], 0, 0, 0);
        }
    }
    __syncthreads();

    // h = relu(acc + b1) -> zt (in place)
#pragma unroll
    for (int nt = 0; nt < 4; ++nt) {
        int col = wn * 64 + nt * 16 + lr;
        float bv = b1[col];
#pragma unroll
        for (int mt = 0; mt < 4; ++mt)
#pragma unroll
            for (int q = 0; q < 4; ++q) {
                int hr = wm * 64 + mt * 16 + lk * 4 + q;
                float hv = fmaxf(acc[mt][nt][q] + bv, 0.f);
                *(__bf16*)&zt[hr * LDR + col] = (__bf16)hv;
            }
    }
    __syncthreads();

    f32x4 acc2[4][4];
#pragma unroll
    for (int mt = 0; mt < 4; ++mt)
#pragma unroll
        for (int nt = 0; nt < 4; ++nt) acc2[mt][nt] = zero4;
#pragma unroll
    for (int kb = 0; kb < 4; ++kb) {
        const int c = kb * 4 + lk;
        bf16x8 a[4];
#pragma unroll
        for (int mt = 0; mt < 4; ++mt)
            a[mt] = *(const bf16x8*)&zt[(wm * 64 + mt * 16 + lr) * LDR + c * 8];
#pragma unroll
        for (int nt = 0; nt < 4; ++nt) {
            bf16x8 b = *(const bf16x8*)&w2T[(wn * 64 + nt * 16 + lr) * 128 + c * 8];
#pragma unroll
            for (int mt = 0; mt < 4; ++mt)
                acc2[mt][nt] = __builtin_amdgcn_mfma_f32_16x16x32_bf16(a[mt], b, acc2[mt][nt], 0, 0, 0);
        }
    }
    __syncthreads();

#pragma unroll
    for (int nt = 0; nt < 4; ++nt) {
        int col = wn * 64 + nt * 16 + lr;
        float bv = b2[col];
#pragma unroll
        for (int mt = 0; mt < 4; ++mt)
#pragma unroll
            for (int q = 0; q < 4; ++q) {
                int orow = wm * 64 + mt * 16 + lk * 4 + q;
                float ov = fmaxf(acc2[mt][nt][q] + bv, 0.f);
                *(__bf16*)&zt[orow * LDR + col] = (__bf16)ov;
            }
    }
    __syncthreads();

    for (int i = t; i < 2048; i += 256) {
        int r = i >> 4, c = i & 15;
        int g = row0 + r;
        if (g < nrows)
            *(bf16x8*)&out[(size_t)g * 128 + c * 8] =
                *(const bf16x8*)&zt[r * LDR + c * 8];
    }
}

// ---------------- fused gather + MLP (layer 1, active set) ----------------
__global__ __launch_bounds__(256, 6) void k_gmlp(const unsigned short* __restrict__ xb,
                                                 const int* __restrict__ rp,
                                                 const int* __restrict__ csr,
                                                 const float* __restrict__ epsp,
                                                 const unsigned short* __restrict__ w1T,
                                                 const float* __restrict__ b1,
                                                 const unsigned short* __restrict__ w2T,
                                                 const float* __restrict__ b2,
                                                 unsigned short* __restrict__ out,
                                                 const int* __restrict__ list,
                                                 const int* __restrict__ cntp, int nrows) {
    __shared__ unsigned short zt[16 * LDR];
    __shared__ unsigned short ht[16 * LDR];
    const int t = threadIdx.x;
    int rows = nrows;
    if (cntp) { int c = *cntp; rows = c < nrows ? c : nrows; }
    const int row0 = blockIdx.x * 16;
    if (row0 >= rows) return;

    {
        const int r16 = t >> 4, lane16 = t & 15;
        int j = row0 + r16;
        bf16x8 zv;
        if (j < rows) {
            int node = list ? list[j] : j;
            int b = rp[node], e = rp[node + 1];
            float s0[8], s1[8];
#pragma unroll
            for (int q = 0; q < 8; ++q) { s0[q] = 0.f; s1[q] = 0.f; }
            int k = b;
            for (; k + 1 < e; k += 2) {
                bf16x8 v0 = *(const bf16x8*)&xb[(size_t)csr[k]     * 128 + lane16 * 8];
                bf16x8 v1 = *(const bf16x8*)&xb[(size_t)csr[k + 1] * 128 + lane16 * 8];
#pragma unroll
                for (int q = 0; q < 8; ++q) { s0[q] += (float)v0[q]; s1[q] += (float)v1[q]; }
            }
            if (k < e) {
                bf16x8 v0 = *(const bf16x8*)&xb[(size_t)csr[k] * 128 + lane16 * 8];
#pragma unroll
                for (int q = 0; q < 8; ++q) s0[q] += (float)v0[q];
            }
            const float epsv = 1.0f + epsp[0];
            bf16x8 xv = *(const bf16x8*)&xb[(size_t)node * 128 + lane16 * 8];
#pragma unroll
            for (int q = 0; q < 8; ++q)
                zv[q] = (__bf16)(epsv * (float)xv[q] + s0[q] + s1[q]);
        } else {
#pragma unroll
            for (int q = 0; q < 8; ++q) zv[q] = (__bf16)0.0f;
        }
        *(bf16x8*)&zt[(t >> 4) * LDR + (t & 15) * 8] = zv;
    }
    __syncthreads();

    const int lane = t & 63;
    const int wave = t >> 6;
    const int lr = lane & 15, lk = lane >> 4;
    const int n0 = wave * 32;

    f32x4 zero4 = {0.f, 0.f, 0.f, 0.f};
    f32x4 acc[2] = {zero4, zero4};
#pragma unroll
    for (int kb = 0; kb < 4; ++kb) {
        bf16x8 a = *(const bf16x8*)&zt[lr * LDR + (kb * 4 + lk) * 8];
#pragma unroll
        for (int nt = 0; nt < 2; ++nt) {
            bf16x8 b = *(const bf16x8*)&w1T[(size_t)(n0 + nt * 16 + lr) * 128 + (kb * 4 + lk) * 8];
            acc[nt] = __builtin_amdgcn_mfma_f32_16x16x32_bf16(a, b, acc[nt], 0, 0, 0);
        }
    }
#pragma unroll
    for (int nt = 0; nt < 2; ++nt) {
        int col = n0 + nt * 16 + lr;
        float bv = b1[col];
#pragma unroll
        for (int q = 0; q < 4; ++q) {
            float hv = fmaxf(acc[nt][q] + bv, 0.f);
            *(__bf16*)&ht[(lk * 4 + q) * LDR + col] = (__bf16)hv;
        }
    }
    __syncthreads();

    f32x4 acc2[2] = {zero4, zero4};
#pragma unroll
    for (int kb = 0; kb < 4; ++kb) {
        bf16x8 a = *(const bf16x8*)&ht[lr * LDR + (kb * 4 + lk) * 8];
#pragma unroll
        for (int nt = 0; nt < 2; ++nt) {
            bf16x8 b = *(const bf16x8*)&w2T[(size_t)(n0 + nt * 16 + lr) * 128 + (kb * 4 + lk) * 8];
            acc2[nt] = __builtin_amdgcn_mfma_f32_16x16x32_bf16(a, b, acc2[nt], 0, 0, 0);
        }
    }
#pragma unroll
    for (int nt = 0; nt < 2; ++nt) {
        int col = n0 + nt * 16 + lr;
        float bv = b2[col];
#pragma unroll
        for (int q = 0; q < 4; ++q) {
            float ov = fmaxf(acc2[nt][q] + bv, 0.f);
            *(__bf16*)&zt[(lk * 4 + q) * LDR + col] = (__bf16)ov;
        }
    }
    __syncthreads();

    {
        int r = t >> 4, c = t & 15;
        int g = row0 + r;
        if (g < rows) {
            int node = list ? list[g] : g;
            *(bf16x8*)&out[(size_t)node * 128 + c * 8] =
                *(const bf16x8*)&zt[r * LDR + c * 8];
        }
    }
}

// ---------------- layer 2 at roots only ----------------
__global__ __launch_bounds__(128) void k_root(const unsigned short* __restrict__ x2,
                                              const int* __restrict__ rp,
                                              const int* __restrict__ csr,
                                              const int* __restrict__ roots,
                                              const float* __restrict__ epsp,
                                              const float* __restrict__ wa,
                                              const float* __restrict__ ba,
                                              const float* __restrict__ wb,
                                              const float* __restrict__ bb,
                                              float* __restrict__ out) {
    __shared__ float hin[128];
    __shared__ float h[64];
    int r = blockIdx.x, t = threadIdx.x;
    int node = roots[r];
    float s = (1.0f + epsp[0]) * (float)(*(const __bf16*)&x2[(size_t)node * 128 + t]);
    int b = rp[node], e = rp[node + 1];
    for (int k = b; k < e; ++k)
        s += (float)(*(const __bf16*)&x2[(size_t)csr[k] * 128 + t]);
    hin[t] = s;
    __syncthreads();
    if (t < 64) {
        float a = ba[t];
        for (int k = 0; k < 128; ++k) a += hin[k] * wa[k * 64 + t];
        h[t] = fmaxf(a, 0.f);
    }
    __syncthreads();
    if (t < 64) {
        float a = bb[t];
        for (int k = 0; k < 64; ++k) a += h[k] * wb[k * 64 + t];
        out[(size_t)r * 64 + t] = a;
    }
}

extern "C" void kernel_launch(void* const* d_in, const int* in_sizes, int n_in,
                              void* d_out, int out_size, void* d_ws, size_t ws_size,
                              hipStream_t stream) {
    const float* x    = (const float*)d_in[0];
    const int*   ei   = (const int*)d_in[1];
    const int*   root = (const int*)d_in[2];
    const float* eps0 = (const float*)d_in[3];
    const float* w0a  = (const float*)d_in[4];
    const float* b0a  = (const float*)d_in[5];
    const float* w0b  = (const float*)d_in[6];
    const float* b0b  = (const float*)d_in[7];
    const float* eps1 = (const float*)d_in[8];
    const float* w1a  = (const float*)d_in[9];
    const float* b1a  = (const float*)d_in[10];
    const float* w1b  = (const float*)d_in[11];
    const float* b1b  = (const float*)d_in[12];
    const float* eps2 = (const float*)d_in[13];
    const float* w2a  = (const float*)d_in[14];
    const float* b2a  = (const float*)d_in[15];
    const float* w2b  = (const float*)d_in[16];
    const float* b2b  = (const float*)d_in[17];

    const int N  = in_sizes[0] / 128;
    const int E  = in_sizes[1] / 2;
    const int NR = in_sizes[2];
    const int MAXACT = 65536;
    const int NB = (N + 127) / 128;           // buckets of 128 nodes (782)
    const int* src = ei;
    const int* dst = ei + E;

    // ---- workspace layout ----
    char* p = (char*)d_ws;
    unsigned short* xb = (unsigned short*)p; p += (size_t)N * 128 * 2;        // 25.6 MB
    unsigned short* x1 = (unsigned short*)p; p += (size_t)N * 128 * 2;        // 25.6 MB
    unsigned short* z0 = (unsigned short*)p; p += (size_t)N * 128 * 2;        // 25.6 MB
    // shared region: ebuf (CSR build) then x2 (layer-1 output) — disjoint
    char* shared0 = p;
    size_t ebuf_bytes = (size_t)NB * CAP * 4;                                 // 25.6 MB
    size_t x2_bytes   = (size_t)N * 128 * 2;                                  // 25.6 MB
    p += (ebuf_bytes > x2_bytes ? ebuf_bytes : x2_bytes);
    unsigned*       ebuf = (unsigned*)shared0;
    unsigned short* x2   = (unsigned short*)shared0;
    unsigned short* wT   = (unsigned short*)p; p += 4 * 128 * 128 * 2;
    int* rp      = (int*)p; p += (size_t)(N + 64) * 4;
    int* list    = (int*)p; p += (size_t)(N + 64) * 4;
    int* boff    = (int*)p; p += 4096;
    // zeroed region (single memset): af | af_root | cnt | gcnt | realcnt
    char* zbeg = p;
    int* af      = (int*)p; p += (size_t)(N + 64) * 4;
    int* af_root = (int*)p; p += (size_t)(N + 64) * 4;
    int* cnt     = (int*)p; p += 256;
    int* gcnt    = (int*)p; p += (size_t)NB * 16 * 4;      // 64B-padded counters
    int* realcnt = (int*)p; p += (size_t)(NB + 64) * 4;
    size_t zbytes = (size_t)(p - zbeg);
    int* csr     = (int*)p; p += (size_t)E * 4;
    unsigned short* w0aT = wT;
    unsigned short* w0bT = wT + 16384;
    unsigned short* w1aT = wT + 32768;
    unsigned short* w1bT = wT + 49152;

    // ---- CSR build + conversions (merged) ----
    hipMemsetAsync(zbeg, 0, zbytes, stream);
    k_scatter<<<256, 1024, 0, stream>>>(src, dst, gcnt, realcnt, ebuf, E, NB,
                                        (const float4*)x, xb, (long)N * 16,
                                        w0a, w0b, w1a, w1b, wT,
                                        root, NR, af_root);
    k_bscan<<<1, 1024, 0, stream>>>(realcnt, boff, rp, NB, N, E);
    k_build<<<NB, 512, 0, stream>>>(ebuf, gcnt, boff, rp, csr, af_root, af, N);

    // ---- layer 0 gather (+ tail-block active-set compaction) ----
    const int segB = (N * 16 + 255) / 256;
    const int cmpB = (N + 255) / 256;
    k_segz<<<segB + cmpB, 256, 0, stream>>>(xb, rp, csr, eps0, z0, N, segB,
                                            af, list, cnt);
    // ---- layer 0 MLP ----
    k_mlp<<<(N + 127) / 128, 256, 0, stream>>>(z0, w0aT, b0a, w0bT, b0b, x1, N);
    // ---- layer 1 (active set only): fused gather+MLP ----
    k_gmlp<<<(MAXACT + 15) / 16, 256, 0, stream>>>(x1, rp, csr, eps1,
                                                   w1aT, b1a, w1bT, b1b,
                                                   x2, list, cnt, MAXACT);
    // ---- layer 2 (roots only) ----
    k_root<<<NR, 128, 0, stream>>>(x2, rp, csr, root, eps2, w2a, b2a, w2b, b2b,
                                   (float*)d_out);
}

// Round 19
// 185.738 us; speedup vs baseline: 1.0692x; 1.0692x over previous
//
#include <hip/hip_runtime.h>

// ---------------------------------------------------------------------------
// GIN 3-layer forward on MI355X (gfx950).
//   - features/weights bf16 node-major (f32 accumulate). Node-major 256B rows
//     gather at ~7.2 TB/s L2-miss fabric traffic = the 8-XCD fabric ceiling
//     (R12-R18: 62us gather invariant; re-layout, fusion into MLP, and
//     wide unrolls all regressed or were neutral).
//   - k_scatter (merged): LDS-binned edge scatter with FULL-LINE flushes
//     (sentinel-padded 64B bursts; this chip's L2 does NOT merge scattered
//     partial-line stores) + x f32->bf16 conversion + weight transpose +
//     root bitmap, all hidden under the latency-bound binning.
//   - k_build (merged): per-bucket histogram -> scan -> rp -> csr slotting,
//     flags root in-neighbors inline (af) via af_root bitmap.
//   - k_segz: max-TLP gather (2-edge unroll); tail blocks run the active-set
//     compaction with HIERARCHICAL atomics (ballot prefix + 1 atomic/block;
//     R18 lesson: flat per-wave atomics on one counter = ~15us serialized).
//   - k_mlp: MFMA 16x16x32 bf16, BM=128, 4 waves, 34.8 KB LDS; B from global
//     (L2-resident); output via LDS -> bf16x8 full-line stores.
//   - k_gmlp (layer 1, 17K rows): fused gather+MLP.
//   - layer 2 only at the 1024 roots.
//   NOTE: edge packing assumes N <= 2^17; bins assume N <= 100352.
// ---------------------------------------------------------------------------

typedef __bf16  bf16x8 __attribute__((ext_vector_type(8)));
typedef float   f32x4  __attribute__((ext_vector_type(4)));

#define NBINS 784     // >= (N+127)/128
#define BCAP  38      // words per LDS bin (per-bin lambda ~8)
#define CAP   8192    // words per global bucket cell (real ~2048 + pads)
#define LDR   136     // LDS row stride in shorts (+8 pad)

// ---------------- merged scatter + conversions + root flag ----------------
__global__ __launch_bounds__(1024) void k_scatter(const int* __restrict__ src,
                                                  const int* __restrict__ dst,
                                                  int* __restrict__ gcnt,     // NB*16 padded
                                                  int* __restrict__ realcnt,  // NB
                                                  unsigned* __restrict__ ebuf,
                                                  int e, int nb,
                                                  const float4* __restrict__ xf,
                                                  unsigned short* __restrict__ xb,
                                                  long n8,
                                                  const float* __restrict__ w0a,
                                                  const float* __restrict__ w0b,
                                                  const float* __restrict__ w1a,
                                                  const float* __restrict__ w1b,
                                                  unsigned short* __restrict__ wT,
                                                  const int* __restrict__ roots,
                                                  int nr,
                                                  int* __restrict__ af_root) {
    __shared__ unsigned lbuf[NBINS * BCAP];   // 119.2 KB
    __shared__ int lcnt[NBINS];
    __shared__ int sbase[NBINS];
    const int t = threadIdx.x;
    for (int b = t; b < nb; b += 1024) lcnt[b] = 0;

    {
        int gi = blockIdx.x * 1024 + t;
        if (gi < nr) af_root[roots[gi]] = 1;
    }
    {
        int gi = blockIdx.x * 1024 + t;
        if (gi < 65536) {
            int m = gi >> 14, j = gi & 16383;
            const float* w = (m == 0) ? w0a : (m == 1) ? w0b : (m == 2) ? w1a : w1b;
            int k = j >> 7, n = j & 127;
            *(__bf16*)&wT[m * 16384 + n * 128 + k] = (__bf16)w[j];
        }
    }
    for (long i = (long)blockIdx.x * 1024 + t; i < n8; i += 262144) {
        float4 a = xf[2 * i], b = xf[2 * i + 1];
        bf16x8 v;
        v[0] = (__bf16)a.x; v[1] = (__bf16)a.y; v[2] = (__bf16)a.z; v[3] = (__bf16)a.w;
        v[4] = (__bf16)b.x; v[5] = (__bf16)b.y; v[6] = (__bf16)b.z; v[7] = (__bf16)b.w;
        *(bf16x8*)&xb[i * 8] = v;
    }
    __syncthreads();

    const int per = (((e + 255) / 256) + 7) & ~7;   // 8-aligned slice, 256 blocks
    const int beg = blockIdx.x * per;
    const int end = (beg + per < e) ? beg + per : e;

    for (int base = beg; base < end; base += 8192) {
        int i0 = base + t * 8;
        if (i0 >= end) continue;
        if (i0 + 8 <= end) {
            int4 s0 = *(const int4*)&src[i0];
            int4 s1 = *(const int4*)&src[i0 + 4];
            int4 d0 = *(const int4*)&dst[i0];
            int4 d1 = *(const int4*)&dst[i0 + 4];
            int ss[8] = {s0.x, s0.y, s0.z, s0.w, s1.x, s1.y, s1.z, s1.w};
            int dd[8] = {d0.x, d0.y, d0.z, d0.w, d1.x, d1.y, d1.z, d1.w};
#pragma unroll
            for (int q = 0; q < 8; ++q) {
                int b = dd[q] >> 7;
                int p = atomicAdd(&lcnt[b], 1);
                if (p < BCAP)
                    lbuf[b * BCAP + p] =
                        (unsigned)ss[q] | ((unsigned)(dd[q] & 127) << 17);
            }
        } else {
            int lim = (i0 + 8 < end) ? i0 + 8 : end;
            for (int i = i0; i < lim; ++i) {
                int d = dst[i];
                int b = d >> 7;
                int p = atomicAdd(&lcnt[b], 1);
                if (p < BCAP)
                    lbuf[b * BCAP + p] =
                        (unsigned)src[i] | ((unsigned)(d & 127) << 17);
            }
        }
    }
    __syncthreads();

    for (int b = t; b < nb; b += 1024) {
        int r = lcnt[b]; if (r > BCAP) r = BCAP;
        int bb = 0;
        if (r > 0) {
            int nf = (r + 15) & ~15;
            bb = atomicAdd(&gcnt[b * 16], nf);
            atomicAdd(&realcnt[b], r);
        }
        sbase[b] = bb;
    }
    __syncthreads();

    const int wave = t >> 6, lane = t & 63;
    const int gidx = wave * 4 + (lane >> 4), sub = lane & 15;
    for (int b = gidx; b < nb; b += 64) {
        int r = lcnt[b]; if (r > BCAP) r = BCAP;
        if (r == 0) continue;
        int nf = (r + 15) & ~15;
        int base2 = sbase[b];
        unsigned* cell = ebuf + (size_t)b * CAP;
        for (int j = sub; j < nf; j += 16) {
            unsigned v = (j < r) ? lbuf[b * BCAP + j] : 0xFFFFFFFFu;
            if (base2 + j < CAP) cell[base2 + j] = v;
        }
    }
}

__global__ __launch_bounds__(1024) void k_bscan(const int* __restrict__ realcnt,
                                                int* __restrict__ boff,
                                                int* __restrict__ rp,
                                                int nb, int n, int e) {
    __shared__ int sh[1024];
    int t = threadIdx.x;
    sh[t] = (t < nb) ? realcnt[t] : 0;
    __syncthreads();
    for (int off = 1; off < 1024; off <<= 1) {
        int u = (t >= off) ? sh[t - off] : 0;
        __syncthreads();
        sh[t] += u;
        __syncthreads();
    }
    if (t < nb) boff[t] = (t == 0) ? 0 : sh[t - 1];
    if (t == 0) rp[n] = e;
}

__global__ __launch_bounds__(512) void k_build(const unsigned* __restrict__ ebuf,
                                               const int* __restrict__ gcnt,
                                               const int* __restrict__ boff,
                                               int* __restrict__ rp,
                                               int* __restrict__ csr,
                                               const int* __restrict__ af_root,
                                               int* __restrict__ af, int n) {
    __shared__ int bins[128];
    __shared__ int incl[128];
    __shared__ int cur[128];
    __shared__ unsigned char isroot[128];
    int b = blockIdx.x, t = threadIdx.x;
    if (t < 128) {
        bins[t] = 0;
        int node = b * 128 + t;
        unsigned char ir = (node < n && af_root[node]) ? 1 : 0;
        isroot[t] = ir;
        if (ir) af[node] = 1;
    }
    __syncthreads();
    int c = gcnt[b * 16]; if (c > CAP) c = CAP;
    const unsigned* seg = ebuf + ((size_t)b * CAP);
    for (int j = t; j < c; j += 512) {
        unsigned w = seg[j];
        if (w != 0xFFFFFFFFu) atomicAdd(&bins[(w >> 17) & 127], 1);
    }
    __syncthreads();
    if (t < 128) incl[t] = bins[t];
    __syncthreads();
    for (int off = 1; off < 128; off <<= 1) {
        int u = (t < 128 && t >= off) ? incl[t - off] : 0;
        __syncthreads();
        if (t < 128) incl[t] += u;
        __syncthreads();
    }
    int base = boff[b];
    if (t < 128) {
        int ex = (t == 0) ? 0 : incl[t - 1];
        cur[t] = ex;
        int node = b * 128 + t;
        if (node < n) rp[node] = base + ex;
    }
    __syncthreads();
    for (int j = t; j < c; j += 512) {
        unsigned w = seg[j];
        if (w != 0xFFFFFFFFu) {
            int ldst = (w >> 17) & 127;
            int s = (int)(w & 0x1FFFF);
            int slot = atomicAdd(&cur[ldst], 1);
            csr[base + slot] = s;
            if (isroot[ldst]) af[s] = 1;
        }
    }
}

// ---------------- gather + GIN update (layer 0) + tail-block compaction ----
// Blocks [0, nsegb): z[j] = (1+eps)*x[j] + sum_{s in N(j)} x[s]; 16 lanes/row,
// 2-edge unroll. Blocks [nsegb, ...): hierarchical active-set compaction —
// ballot prefix per wave + LDS scan + ONE global atomic per block (R18
// lesson: flat per-wave atomics on one counter serialize ~15us).
__global__ __launch_bounds__(256) void k_segz(const unsigned short* __restrict__ xb,
                                              const int* __restrict__ rp,
                                              const int* __restrict__ csr,
                                              const float* __restrict__ epsp,
                                              unsigned short* __restrict__ zout,
                                              int n, int nsegb,
                                              const int* __restrict__ af,
                                              int* __restrict__ list,
                                              int* __restrict__ cnt) {
    if ((int)blockIdx.x >= nsegb) {
        __shared__ int wsum[4];
        __shared__ int bbase;
        const int t = threadIdx.x;
        const int wid = t >> 6, lane = t & 63;
        int i = (blockIdx.x - nsegb) * 256 + t;
        int active = (i < n && af[i]) ? 1 : 0;
        unsigned long long m = __ballot(active);
        int before = __popcll(m & ((lane == 0) ? 0ull : (~0ull >> (64 - lane))));
        if (lane == 0) wsum[wid] = __popcll(m);
        __syncthreads();
        if (t == 0) {
            int s0 = wsum[0], s1 = wsum[1], s2 = wsum[2], s3 = wsum[3];
            bbase = atomicAdd(cnt, s0 + s1 + s2 + s3);
            wsum[0] = 0; wsum[1] = s0; wsum[2] = s0 + s1; wsum[3] = s0 + s1 + s2;
        }
        __syncthreads();
        if (active) list[bbase + wsum[wid] + before] = i;
        return;
    }
    int gid = blockIdx.x * 256 + threadIdx.x;
    int j = gid >> 4, lane = gid & 15;
    if (j >= n) return;
    int b = rp[j], e = rp[j + 1];
    float s0[8], s1[8];
#pragma unroll
    for (int q = 0; q < 8; ++q) { s0[q] = 0.f; s1[q] = 0.f; }
    int k = b;
    for (; k + 1 < e; k += 2) {
        bf16x8 v0 = *(const bf16x8*)&xb[(size_t)csr[k]     * 128 + lane * 8];
        bf16x8 v1 = *(const bf16x8*)&xb[(size_t)csr[k + 1] * 128 + lane * 8];
#pragma unroll
        for (int q = 0; q < 8; ++q) { s0[q] += (float)v0[q]; s1[q] += (float)v1[q]; }
    }
    if (k < e) {
        bf16x8 v0 = *(const bf16x8*)&xb[(size_t)csr[k] * 128 + lane * 8];
#pragma unroll
        for (int q = 0; q < 8; ++q) s0[q] += (float)v0[q];
    }
    const float epsv = 1.0f + epsp[0];
    bf16x8 xv = *(const bf16x8*)&xb[(size_t)j * 128 + lane * 8];
    bf16x8 o;
#pragma unroll
    for (int q = 0; q < 8; ++q)
        o[q] = (__bf16)(epsv * (float)xv[q] + s0[q] + s1[q]);
    *(bf16x8*)&zout[(size_t)j * 128 + lane * 8] = o;
}

// ---------------- MLP (layer 0): out = relu( relu(z@w1+b1) @ w2 + b2 ) ----
__global__ __launch_bounds__(256) void k_mlp(const unsigned short* __restrict__ zbuf,
                                             const unsigned short* __restrict__ w1T,
                                             const float* __restrict__ b1,
                                             const unsigned short* __restrict__ w2T,
                                             const float* __restrict__ b2,
                                             unsigned short* __restrict__ out,
                                             int nrows) {
    __shared__ unsigned short zt[128 * LDR];   // 34.8 KB
    const int t = threadIdx.x;
    const int row0 = blockIdx.x * 128;
    if (row0 >= nrows) return;

    for (int i = t; i < 2048; i += 256) {
        int r = i >> 4, c = i & 15;
        int g = row0 + r;
        bf16x8 zv;
        if (g < nrows) {
            zv = *(const bf16x8*)&zbuf[(size_t)g * 128 + c * 8];
        } else {
#pragma unroll
            for (int q = 0; q < 8; ++q) zv[q] = (__bf16)0.0f;
        }
        *(bf16x8*)&zt[r * LDR + c * 8] = zv;
    }
    __syncthreads();

    const int lane = t & 63;
    const int wm = (t >> 7) & 1, wn = (t >> 6) & 1;
    const int lr = lane & 15, lk = lane >> 4;

    f32x4 zero4 = {0.f, 0.f, 0.f, 0.f};
    f32x4 acc[4][4];
#pragma unroll
    for (int mt = 0; mt < 4; ++mt)
#pragma unroll
        for (int nt = 0; nt < 4; ++nt) acc[mt][nt] = zero4;

#pragma unroll
    for (int kb = 0; kb < 4; ++kb) {
        const int c = kb * 4 + lk;
        bf16x8 a[4];
#pragma unroll
        for (int mt = 0; mt < 4; ++mt)
            a[mt] = *(const bf16x8*)&zt[(wm * 64 + mt * 16 + lr) * LDR + c * 8];
#pragma unroll
        for (int nt = 0; nt < 4; ++nt) {
            bf16x8 b = *(const bf16x8*)&w1T[(wn * 64 + nt * 16 + lr) * 128 + c * 8];
#pragma unroll
            for (int mt = 0; mt < 4; ++mt)
                acc[mt][nt] = __builtin_amdgcn_mfma_f32_16x16x32_bf16(a[mt], b, acc[mt][nt], 0, 0, 0);
        }
    }
    __syncthreads();

    // h = relu(acc + b1) -> zt (in place)
#pragma unroll
    for (int nt = 0; nt < 4; ++nt) {
        int col = wn * 64 + nt * 16 + lr;
        float bv = b1[col];
#pragma unroll
        for (int mt = 0; mt < 4; ++mt)
#pragma unroll
            for (int q = 0; q < 4; ++q) {
                int hr = wm * 64 + mt * 16 + lk * 4 + q;
                float hv = fmaxf(acc[mt][nt][q] + bv, 0.f);
                *(__bf16*)&zt[hr * LDR + col] = (__bf16)hv;
            }
    }
    __syncthreads();

    f32x4 acc2[4][4];
#pragma unroll
    for (int mt = 0; mt < 4; ++mt)
#pragma unroll
        for (int nt = 0; nt < 4; ++nt) acc2[mt][nt] = zero4;
#pragma unroll
    for (int kb = 0; kb < 4; ++kb) {
        const int c = kb * 4 + lk;
        bf16x8 a[4];
#pragma unroll
        for (int mt = 0; mt < 4; ++mt)
            a[mt] = *(const bf16x8*)&zt[(wm * 64 + mt * 16 + lr) * LDR + c * 8];
#pragma unroll
        for (int nt = 0; nt < 4; ++nt) {
            bf16x8 b = *(const bf16x8*)&w2T[(wn * 64 + nt * 16 + lr) * 128 + c * 8];
#pragma unroll
            for (int mt = 0; mt < 4; ++mt)
                acc2[mt][nt] = __builtin_amdgcn_mfma_f32_16x16x32_bf16(a[mt], b, acc2[mt][nt], 0, 0, 0);
        }
    }
    __syncthreads();

#pragma unroll
    for (int nt = 0; nt < 4; ++nt) {
        int col = wn * 64 + nt * 16 + lr;
        float bv = b2[col];
#pragma unroll
        for (int mt = 0; mt < 4; ++mt)
#pragma unroll
            for (int q = 0; q < 4; ++q) {
                int orow = wm * 64 + mt * 16 + lk * 4 + q;
                float ov = fmaxf(acc2[mt][nt][q] + bv, 0.f);
                *(__bf16*)&zt[orow * LDR + col] = (__bf16)ov;
            }
    }
    __syncthreads();

    for (int i = t; i < 2048; i += 256) {
        int r = i >> 4, c = i & 15;
        int g = row0 + r;
        if (g < nrows)
            *(bf16x8*)&out[(size_t)g * 128 + c * 8] =
                *(const bf16x8*)&zt[r * LDR + c * 8];
    }
}

// ---------------- fused gather + MLP (layer 1, active set) ----------------
__global__ __launch_bounds__(256, 6) void k_gmlp(const unsigned short* __restrict__ xb,
                                                 const int* __restrict__ rp,
                                                 const int* __restrict__ csr,
                                                 const float* __restrict__ epsp,
                                                 const unsigned short* __restrict__ w1T,
                                                 const float* __restrict__ b1,
                                                 const unsigned short* __restrict__ w2T,
                                                 const float* __restrict__ b2,
                                                 unsigned short* __restrict__ out,
                                                 const int* __restrict__ list,
                                                 const int* __restrict__ cntp, int nrows) {
    __shared__ unsigned short zt[16 * LDR];
    __shared__ unsigned short ht[16 * LDR];
    const int t = threadIdx.x;
    int rows = nrows;
    if (cntp) { int c = *cntp; rows = c < nrows ? c : nrows; }
    const int row0 = blockIdx.x * 16;
    if (row0 >= rows) return;

    {
        const int r16 = t >> 4, lane16 = t & 15;
        int j = row0 + r16;
        bf16x8 zv;
        if (j < rows) {
            int node = list ? list[j] : j;
            int b = rp[node], e = rp[node + 1];
            float s0[8], s1[8];
#pragma unroll
            for (int q = 0; q < 8; ++q) { s0[q] = 0.f; s1[q] = 0.f; }
            int k = b;
            for (; k + 1 < e; k += 2) {
                bf16x8 v0 = *(const bf16x8*)&xb[(size_t)csr[k]     * 128 + lane16 * 8];
                bf16x8 v1 = *(const bf16x8*)&xb[(size_t)csr[k + 1] * 128 + lane16 * 8];
#pragma unroll
                for (int q = 0; q < 8; ++q) { s0[q] += (float)v0[q]; s1[q] += (float)v1[q]; }
            }
            if (k < e) {
                bf16x8 v0 = *(const bf16x8*)&xb[(size_t)csr[k] * 128 + lane16 * 8];
#pragma unroll
                for (int q = 0; q < 8; ++q) s0[q] += (float)v0[q];
            }
            const float epsv = 1.0f + epsp[0];
            bf16x8 xv = *(const bf16x8*)&xb[(size_t)node * 128 + lane16 * 8];
#pragma unroll
            for (int q = 0; q < 8; ++q)
                zv[q] = (__bf16)(epsv * (float)xv[q] + s0[q] + s1[q]);
        } else {
#pragma unroll
            for (int q = 0; q < 8; ++q) zv[q] = (__bf16)0.0f;
        }
        *(bf16x8*)&zt[(t >> 4) * LDR + (t & 15) * 8] = zv;
    }
    __syncthreads();

    const int lane = t & 63;
    const int wave = t >> 6;
    const int lr = lane & 15, lk = lane >> 4;
    const int n0 = wave * 32;

    f32x4 zero4 = {0.f, 0.f, 0.f, 0.f};
    f32x4 acc[2] = {zero4, zero4};
#pragma unroll
    for (int kb = 0; kb < 4; ++kb) {
        bf16x8 a = *(const bf16x8*)&zt[lr * LDR + (kb * 4 + lk) * 8];
#pragma unroll
        for (int nt = 0; nt < 2; ++nt) {
            bf16x8 b = *(const bf16x8*)&w1T[(size_t)(n0 + nt * 16 + lr) * 128 + (kb * 4 + lk) * 8];
            acc[nt] = __builtin_amdgcn_mfma_f32_16x16x32_bf16(a, b, acc[nt], 0, 0, 0);
        }
    }
#pragma unroll
    for (int nt = 0; nt < 2; ++nt) {
        int col = n0 + nt * 16 + lr;
        float bv = b1[col];
#pragma unroll
        for (int q = 0; q < 4; ++q) {
            float hv = fmaxf(acc[nt][q] + bv, 0.f);
            *(__bf16*)&ht[(lk * 4 + q) * LDR + col] = (__bf16)hv;
        }
    }
    __syncthreads();

    f32x4 acc2[2] = {zero4, zero4};
#pragma unroll
    for (int kb = 0; kb < 4; ++kb) {
        bf16x8 a = *(const bf16x8*)&ht[lr * LDR + (kb * 4 + lk) * 8];
#pragma unroll
        for (int nt = 0; nt < 2; ++nt) {
            bf16x8 b = *(const bf16x8*)&w2T[(size_t)(n0 + nt * 16 + lr) * 128 + (kb * 4 + lk) * 8];
            acc2[nt] = __builtin_amdgcn_mfma_f32_16x16x32_bf16(a, b, acc2[nt], 0, 0, 0);
        }
    }
#pragma unroll
    for (int nt = 0; nt < 2; ++nt) {
        int col = n0 + nt * 16 + lr;
        float bv = b2[col];
#pragma unroll
        for (int q = 0; q < 4; ++q) {
            float ov = fmaxf(acc2[nt][q] + bv, 0.f);
            *(__bf16*)&zt[(lk * 4 + q) * LDR + col] = (__bf16)ov;
        }
    }
    __syncthreads();

    {
        int r = t >> 4, c = t & 15;
        int g = row0 + r;
        if (g < rows) {
            int node = list ? list[g] : g;
            *(bf16x8*)&out[(size_t)node * 128 + c * 8] =
                *(const bf16x8*)&zt[r * LDR + c * 8];
        }
    }
}

// ---------------- layer 2 at roots only ----------------
__global__ __launch_bounds__(128) void k_root(const unsigned short* __restrict__ x2,
                                              const int* __restrict__ rp,
                                              const int* __restrict__ csr,
                                              const int* __restrict__ roots,
                                              const float* __restrict__ epsp,
                                              const float* __restrict__ wa,
                                              const float* __restrict__ ba,
                                              const float* __restrict__ wb,
                                              const float* __restrict__ bb,
                                              float* __restrict__ out) {
    __shared__ float hin[128];
    __shared__ float h[64];
    int r = blockIdx.x, t = threadIdx.x;
    int node = roots[r];
    float s = (1.0f + epsp[0]) * (float)(*(const __bf16*)&x2[(size_t)node * 128 + t]);
    int b = rp[node], e = rp[node + 1];
    for (int k = b; k < e; ++k)
        s += (float)(*(const __bf16*)&x2[(size_t)csr[k] * 128 + t]);
    hin[t] = s;
    __syncthreads();
    if (t < 64) {
        float a = ba[t];
        for (int k = 0; k < 128; ++k) a += hin[k] * wa[k * 64 + t];
        h[t] = fmaxf(a, 0.f);
    }
    __syncthreads();
    if (t < 64) {
        float a = bb[t];
        for (int k = 0; k < 64; ++k) a += h[k] * wb[k * 64 + t];
        out[(size_t)r * 64 + t] = a;
    }
}

extern "C" void kernel_launch(void* const* d_in, const int* in_sizes, int n_in,
                              void* d_out, int out_size, void* d_ws, size_t ws_size,
                              hipStream_t stream) {
    const float* x    = (const float*)d_in[0];
    const int*   ei   = (const int*)d_in[1];
    const int*   root = (const int*)d_in[2];
    const float* eps0 = (const float*)d_in[3];
    const float* w0a  = (const float*)d_in[4];
    const float* b0a  = (const float*)d_in[5];
    const float* w0b  = (const float*)d_in[6];
    const float* b0b  = (const float*)d_in[7];
    const float* eps1 = (const float*)d_in[8];
    const float* w1a  = (const float*)d_in[9];
    const float* b1a  = (const float*)d_in[10];
    const float* w1b  = (const float*)d_in[11];
    const float* b1b  = (const float*)d_in[12];
    const float* eps2 = (const float*)d_in[13];
    const float* w2a  = (const float*)d_in[14];
    const float* b2a  = (const float*)d_in[15];
    const float* w2b  = (const float*)d_in[16];
    const float* b2b  = (const float*)d_in[17];

    const int N  = in_sizes[0] / 128;
    const int E  = in_sizes[1] / 2;
    const int NR = in_sizes[2];
    const int MAXACT = 65536;
    const int NB = (N + 127) / 128;           // buckets of 128 nodes (782)
    const int* src = ei;
    const int* dst = ei + E;

    // ---- workspace layout ----
    char* p = (char*)d_ws;
    unsigned short* xb = (unsigned short*)p; p += (size_t)N * 128 * 2;        // 25.6 MB
    unsigned short* x1 = (unsigned short*)p; p += (size_t)N * 128 * 2;        // 25.6 MB
    unsigned short* z0 = (unsigned short*)p; p += (size_t)N * 128 * 2;        // 25.6 MB
    // shared region: ebuf (CSR build) then x2 (layer-1 output) — disjoint
    char* shared0 = p;
    size_t ebuf_bytes = (size_t)NB * CAP * 4;                                 // 25.6 MB
    size_t x2_bytes   = (size_t)N * 128 * 2;                                  // 25.6 MB
    p += (ebuf_bytes > x2_bytes ? ebuf_bytes : x2_bytes);
    unsigned*       ebuf = (unsigned*)shared0;
    unsigned short* x2   = (unsigned short*)shared0;
    unsigned short* wT   = (unsigned short*)p; p += 4 * 128 * 128 * 2;
    int* rp      = (int*)p; p += (size_t)(N + 64) * 4;
    int* list    = (int*)p; p += (size_t)(N + 64) * 4;
    int* boff    = (int*)p; p += 4096;
    // zeroed region (single memset): af | af_root | cnt | gcnt | realcnt
    char* zbeg = p;
    int* af      = (int*)p; p += (size_t)(N + 64) * 4;
    int* af_root = (int*)p; p += (size_t)(N + 64) * 4;
    int* cnt     = (int*)p; p += 256;
    int* gcnt    = (int*)p; p += (size_t)NB * 16 * 4;      // 64B-padded counters
    int* realcnt = (int*)p; p += (size_t)(NB + 64) * 4;
    size_t zbytes = (size_t)(p - zbeg);
    int* csr     = (int*)p; p += (size_t)E * 4;
    unsigned short* w0aT = wT;
    unsigned short* w0bT = wT + 16384;
    unsigned short* w1aT = wT + 32768;
    unsigned short* w1bT = wT + 49152;

    // ---- CSR build + conversions (merged) ----
    hipMemsetAsync(zbeg, 0, zbytes, stream);
    k_scatter<<<256, 1024, 0, stream>>>(src, dst, gcnt, realcnt, ebuf, E, NB,
                                        (const float4*)x, xb, (long)N * 16,
                                        w0a, w0b, w1a, w1b, wT,
                                        root, NR, af_root);
    k_bscan<<<1, 1024, 0, stream>>>(realcnt, boff, rp, NB, N, E);
    k_build<<<NB, 512, 0, stream>>>(ebuf, gcnt, boff, rp, csr, af_root, af, N);

    // ---- layer 0 gather (+ tail-block hierarchical compaction) ----
    const int segB = (N * 16 + 255) / 256;
    const int cmpB = (N + 255) / 256;
    k_segz<<<segB + cmpB, 256, 0, stream>>>(xb, rp, csr, eps0, z0, N, segB,
                                            af, list, cnt);
    // ---- layer 0 MLP ----
    k_mlp<<<(N + 127) / 128, 256, 0, stream>>>(z0, w0aT, b0a, w0bT, b0b, x1, N);
    // ---- layer 1 (active set only): fused gather+MLP ----
    k_gmlp<<<(MAXACT + 15) / 16, 256, 0, stream>>>(x1, rp, csr, eps1,
                                                   w1aT, b1a, w1bT, b1b,
                                                   x2, list, cnt, MAXACT);
    // ---- layer 2 (roots only) ----
    k_root<<<NR, 128, 0, stream>>>(x2, rp, csr, root, eps2, w2a, b2a, w2b, b2b,
                                   (float*)d_out);
}